// Round 1
// baseline (742.489 us; speedup 1.0000x reference)
//
#include <hip/hip_runtime.h>
#include <math.h>
#include <cstddef>

// Problem constants
#define BB   16
#define HH   256
#define WW   256
#define CC   64      // channels (= attention token count)
#define NTOK 16      // pooled tokens per (b,c)
#define NDIM 16      // DIM

// ws layout (floats):
//   part : [B][16 tok][16 rc][64 c]  = 262144 floats (1 MiB)
//   attnT: [B][64 c][64 t]           =  65536 floats (256 KiB)
#define PART_FLOATS (BB * NTOK * 16 * CC)

// ---------------------------------------------------------------------------
// Stage 1: partial pooling sums.
// grid = B*16tok*16rc = 4096 blocks, 256 threads.
// Block handles a 4-row x 64-col strip of one 64x64 patch, all 64 channels.
// Thread t: c4 = (t&15)*4, sub = t>>4 ; positions pos = sub + 16k, k<16.
// Wave reads 1 KiB fully-coalesced per float4 instruction.
// ---------------------------------------------------------------------------
__global__ __launch_bounds__(256) void pool_partial(const float* __restrict__ x,
                                                    float* __restrict__ part) {
    const int blk = blockIdx.x;       // b*256 + n*16 + rc
    const int rc  = blk & 15;
    const int n   = (blk >> 4) & 15;
    const int b   = blk >> 8;
    const int ph  = n >> 2, pw = n & 3;
    const int t   = threadIdx.x;
    const int c4  = (t & 15) << 2;
    const int sub = t >> 4;           // 0..15

    const int h0 = ph * 64 + rc * 4;
    const int w0 = pw * 64;
    const float* xb = x + (((size_t)b * HH + h0) * WW + w0) * CC;

    float4 s = make_float4(0.f, 0.f, 0.f, 0.f);
#pragma unroll
    for (int k = 0; k < 16; ++k) {
        const int pos = sub + (k << 4);       // 0..255
        const int row = pos >> 6;
        const int col = pos & 63;
        const float4 v = *(const float4*)(xb + ((size_t)row * WW + col) * CC + c4);
        s.x += v.x; s.y += v.y; s.z += v.z; s.w += v.w;
    }

    __shared__ float lds[16 * 64];
    lds[sub * 64 + c4 + 0] = s.x;
    lds[sub * 64 + c4 + 1] = s.y;
    lds[sub * 64 + c4 + 2] = s.z;
    lds[sub * 64 + c4 + 3] = s.w;
    __syncthreads();

    if (t < 64) {
        float acc = 0.f;
#pragma unroll
        for (int ss = 0; ss < 16; ++ss) acc += lds[ss * 64 + t];
        part[(((size_t)b * NTOK + n) * 16 + rc) * CC + t] = acc;
    }
}

// ---------------------------------------------------------------------------
// Stage 2: tokens -> qk -> dots -> softmax -> attnT. grid = 16 (one per batch).
// attnT[b][c][t] = attn[b][t][c]  (t contiguous, for stage-3 scalar loads)
// ---------------------------------------------------------------------------
__global__ __launch_bounds__(256) void attn_kernel(const float* __restrict__ part,
                                                   const float* __restrict__ w_qkv, // [32][16]
                                                   float* __restrict__ attnT) {
    const int b = blockIdx.x;
    const int t = threadIdx.x;

    __shared__ float tok[CC * NDIM];   // [c][n]
    __shared__ float ql [CC * NDIM];   // [c][n]
    __shared__ float kl [CC * NDIM];   // [c][n]
    __shared__ float dl [CC * CC];     // [i][j]
    __shared__ float rs [CC];          // 1/rowsum

    const float* pb = part + (size_t)b * NTOK * 16 * CC;

    // tokens[c][n] = mean over patch = (sum of 16 rc-partials)/4096
    for (int idx = t; idx < CC * NDIM; idx += 256) {
        const int c = idx >> 4, n = idx & 15;
        float a = 0.f;
#pragma unroll
        for (int rc = 0; rc < 16; ++rc) a += pb[((size_t)n * 16 + rc) * CC + c];
        tok[c * NDIM + n] = a * (1.0f / 4096.0f);
    }
    __syncthreads();

    // qk[c][d] = sum_n tok[c][n] * w[d][n];  split into q (d<16) and k
    for (int idx = t; idx < CC * 32; idx += 256) {
        const int c = idx >> 5, d = idx & 31;
        float a = 0.f;
#pragma unroll
        for (int n = 0; n < NDIM; ++n) a += tok[c * NDIM + n] * w_qkv[d * NDIM + n];
        if (d < 16) ql[c * NDIM + d] = a;
        else        kl[c * NDIM + (d - 16)] = a;
    }
    __syncthreads();

    // dots[i][j] = 0.25 * sum_n q[i][n]*k[j][n]
    for (int idx = t; idx < CC * CC; idx += 256) {
        const int i = idx >> 6, j = idx & 63;
        float a = 0.f;
#pragma unroll
        for (int n = 0; n < NDIM; ++n) a += ql[i * NDIM + n] * kl[j * NDIM + n];
        dl[idx] = a * 0.25f;
    }
    __syncthreads();

    // row softmax (64 rows, one thread each — tiny)
    if (t < CC) {
        float m = -1e30f;
        for (int j = 0; j < CC; ++j) m = fmaxf(m, dl[t * CC + j]);
        float ssum = 0.f;
        for (int j = 0; j < CC; ++j) {
            const float e = expf(dl[t * CC + j] - m);
            dl[t * CC + j] = e;
            ssum += e;
        }
        rs[t] = 1.0f / ssum;
    }
    __syncthreads();

    // attnT[b][c][t2] = dl[t2][c] * rs[t2]
    for (int idx = t; idx < CC * CC; idx += 256) {
        const int tt = idx & 63;        // idx = c*64 + t2
        attnT[(size_t)b * (CC * CC) + idx] = dl[tt * CC + (idx >> 6)] * rs[tt];
    }
}

// ---------------------------------------------------------------------------
// Stage 3: out[p][t] = gelu( sum_c x[p][c] * attnT[c][t] )
// grid = 4096 blocks x 256 threads; one pixel per lane, 64 fp32 accumulators.
// attnT rows are wave-uniform const loads -> s_load (SGPR operand in v_fmac).
// ---------------------------------------------------------------------------
__device__ __forceinline__ float gelu_exact(float v) {
    return 0.5f * v * (1.0f + erff(v * 0.70710678118654752f));
}

__global__ __launch_bounds__(256) void out_kernel(const float* __restrict__ x,
                                                  const float* __restrict__ attnT,
                                                  float* __restrict__ out) {
    const int blk = blockIdx.x;                // b = blk>>8
    const int b   = blk >> 8;
    const size_t p = ((size_t)blk << 8) + threadIdx.x;   // global pixel index
    const float* __restrict__ xr = x + p * CC;
    const float* __restrict__ at = attnT + (size_t)b * (CC * CC);

    float acc[CC];
#pragma unroll
    for (int t2 = 0; t2 < CC; ++t2) acc[t2] = 0.f;

#pragma unroll 1
    for (int cc = 0; cc < CC; cc += 4) {
        const float4 v = *(const float4*)(xr + cc);
        const float xs[4] = {v.x, v.y, v.z, v.w};
#pragma unroll
        for (int ci = 0; ci < 4; ++ci) {
            const float xc = xs[ci];
            const float* __restrict__ ar = at + (size_t)(cc + ci) * CC;
#pragma unroll
            for (int t2 = 0; t2 < CC; ++t2) {
                acc[t2] = fmaf(xc, ar[t2], acc[t2]);
            }
        }
    }

    float* op = out + p * CC;
#pragma unroll
    for (int t2 = 0; t2 < CC; t2 += 4) {
        float4 g;
        g.x = gelu_exact(acc[t2 + 0]);
        g.y = gelu_exact(acc[t2 + 1]);
        g.z = gelu_exact(acc[t2 + 2]);
        g.w = gelu_exact(acc[t2 + 3]);
        *(float4*)(op + t2) = g;
    }
}

// ---------------------------------------------------------------------------
extern "C" void kernel_launch(void* const* d_in, const int* in_sizes, int n_in,
                              void* d_out, int out_size, void* d_ws, size_t ws_size,
                              hipStream_t stream) {
    const float* x     = (const float*)d_in[0];   // (16,256,256,64) fp32
    const float* w_qkv = (const float*)d_in[1];   // (32,16) fp32
    float* out   = (float*)d_out;                 // (16,256,256,64) fp32
    float* part  = (float*)d_ws;                  // 1 MiB
    float* attnT = part + PART_FLOATS;            // 256 KiB

    pool_partial<<<BB * NTOK * 16, 256, 0, stream>>>(x, part);
    attn_kernel<<<BB, 256, 0, stream>>>(part, w_qkv, attnT);
    out_kernel<<<BB * 256, 256, 0, stream>>>(x, attnT, out);
}

// Round 2
// 561.905 us; speedup vs baseline: 1.3214x; 1.3214x over previous
//
#include <hip/hip_runtime.h>
#include <math.h>
#include <cstddef>

// Problem constants
#define BB   16
#define HH   256
#define WW   256
#define CC   64      // channels (= attention token count)
#define NTOK 16      // pooled tokens per (b,c)
#define NDIM 16      // DIM

// ws layout (floats):
//   part : [B][16 tok][16 rc][64 c]  = 262144 floats (1 MiB)
//   attnT: [B][64 c][64 t]           =  65536 floats (256 KiB)
#define PART_FLOATS (BB * NTOK * 16 * CC)

// ---------------------------------------------------------------------------
// Stage 1: partial pooling sums.
// grid = B*16tok*16rc = 4096 blocks, 256 threads.
// Block handles a 4-row x 64-col strip of one 64x64 patch, all 64 channels.
// Wave reads 1 KiB fully-coalesced per float4 instruction.
// ---------------------------------------------------------------------------
__global__ __launch_bounds__(256) void pool_partial(const float* __restrict__ x,
                                                    float* __restrict__ part) {
    const int blk = blockIdx.x;       // b*256 + n*16 + rc
    const int rc  = blk & 15;
    const int n   = (blk >> 4) & 15;
    const int b   = blk >> 8;
    const int ph  = n >> 2, pw = n & 3;
    const int t   = threadIdx.x;
    const int c4  = (t & 15) << 2;
    const int sub = t >> 4;           // 0..15

    const int h0 = ph * 64 + rc * 4;
    const int w0 = pw * 64;
    const float* xb = x + (((size_t)b * HH + h0) * WW + w0) * CC;

    float4 s = make_float4(0.f, 0.f, 0.f, 0.f);
#pragma unroll
    for (int k = 0; k < 16; ++k) {
        const int pos = sub + (k << 4);       // 0..255
        const int row = pos >> 6;
        const int col = pos & 63;
        const float4 v = *(const float4*)(xb + ((size_t)row * WW + col) * CC + c4);
        s.x += v.x; s.y += v.y; s.z += v.z; s.w += v.w;
    }

    __shared__ float lds[16 * 64];
    lds[sub * 64 + c4 + 0] = s.x;
    lds[sub * 64 + c4 + 1] = s.y;
    lds[sub * 64 + c4 + 2] = s.z;
    lds[sub * 64 + c4 + 3] = s.w;
    __syncthreads();

    if (t < 64) {
        float acc = 0.f;
#pragma unroll
        for (int ss = 0; ss < 16; ++ss) acc += lds[ss * 64 + t];
        part[(((size_t)b * NTOK + n) * 16 + rc) * CC + t] = acc;
    }
}

// ---------------------------------------------------------------------------
// Stage 2: tokens -> qk -> dots -> softmax -> attnT. grid = 16 (one per batch).
// attnT[b][c][t] = attn[b][t][c]  (t contiguous, for stage-3 uniform loads)
// ---------------------------------------------------------------------------
__global__ __launch_bounds__(256) void attn_kernel(const float* __restrict__ part,
                                                   const float* __restrict__ w_qkv, // [32][16]
                                                   float* __restrict__ attnT) {
    const int b = blockIdx.x;
    const int t = threadIdx.x;

    __shared__ float tok[CC * NDIM];   // [c][n]
    __shared__ float ql [CC * NDIM];   // [c][n]
    __shared__ float kl [CC * NDIM];   // [c][n]
    __shared__ float dl [CC * CC];     // [i][j]
    __shared__ float rs [CC];          // 1/rowsum

    const float* pb = part + (size_t)b * NTOK * 16 * CC;

    // tokens[c][n] = mean over patch = (sum of 16 rc-partials)/4096
    for (int idx = t; idx < CC * NDIM; idx += 256) {
        const int c = idx >> 4, n = idx & 15;
        float a = 0.f;
#pragma unroll
        for (int rc = 0; rc < 16; ++rc) a += pb[((size_t)n * 16 + rc) * CC + c];
        tok[c * NDIM + n] = a * (1.0f / 4096.0f);
    }
    __syncthreads();

    // qk[c][d] = sum_n tok[c][n] * w[d][n];  split into q (d<16) and k
    for (int idx = t; idx < CC * 32; idx += 256) {
        const int c = idx >> 5, d = idx & 31;
        float a = 0.f;
#pragma unroll
        for (int n = 0; n < NDIM; ++n) a += tok[c * NDIM + n] * w_qkv[d * NDIM + n];
        if (d < 16) ql[c * NDIM + d] = a;
        else        kl[c * NDIM + (d - 16)] = a;
    }
    __syncthreads();

    // dots[i][j] = 0.25 * sum_n q[i][n]*k[j][n]
    for (int idx = t; idx < CC * CC; idx += 256) {
        const int i = idx >> 6, j = idx & 63;
        float a = 0.f;
#pragma unroll
        for (int n = 0; n < NDIM; ++n) a += ql[i * NDIM + n] * kl[j * NDIM + n];
        dl[idx] = a * 0.25f;
    }
    __syncthreads();

    // row softmax (64 rows, one thread each — tiny)
    if (t < CC) {
        float m = -1e30f;
        for (int j = 0; j < CC; ++j) m = fmaxf(m, dl[t * CC + j]);
        float ssum = 0.f;
        for (int j = 0; j < CC; ++j) {
            const float e = expf(dl[t * CC + j] - m);
            dl[t * CC + j] = e;
            ssum += e;
        }
        rs[t] = 1.0f / ssum;
    }
    __syncthreads();

    // attnT[b][c][t2] = dl[t2][c] * rs[t2]
    for (int idx = t; idx < CC * CC; idx += 256) {
        const int tt = idx & 63;        // idx = c*64 + t2
        attnT[(size_t)b * (CC * CC) + idx] = dl[tt * CC + (idx >> 6)] * rs[tt];
    }
}

// ---------------------------------------------------------------------------
// Stage 3: out[p][t] = gelu( sum_c x[p][c] * attnT[c][t] )
// Block = 256 threads = 4 waves, handles 64 pixels. Thread (lane=pixel,
// th=waveId) computes 16 tokens -> only 16 fp32 accumulators/lane (no spill;
// round-1 version spilled acc[64] to scratch: VGPR_Count=40, FETCH 760MB).
// th is wave-uniform (readfirstlane) so attn chunk loads are scalar s_loads.
// x is staged via LDS: coalesced float4 global loads; stride-65 padding makes
// the per-c LDS reads 2-lanes/bank (free, m136).
// ---------------------------------------------------------------------------
__device__ __forceinline__ float gelu_exact(float v) {
    return 0.5f * v * (1.0f + erff(v * 0.70710678118654752f));
}

#define XPAD 65   // LDS row stride in floats

__global__ __launch_bounds__(256) void out_kernel(const float* __restrict__ x,
                                                  const float* __restrict__ attnT,
                                                  float* __restrict__ out) {
    const int tid  = threadIdx.x;
    const int lane = tid & 63;                               // pixel within block
    const int th   = __builtin_amdgcn_readfirstlane(tid >> 6); // token quarter, wave-uniform
    const int blk  = blockIdx.x;                             // 16384 blocks
    const int b    = blk >> 10;                              // 1024 blocks per batch
    const size_t pixbase = (size_t)blk * 64;

    __shared__ float xt[64 * XPAD];

    // Cooperative stage of 64 pixel rows (16 KiB): 1024 float4 loads, coalesced.
    const float4* xsrc = (const float4*)(x + pixbase * CC);
#pragma unroll
    for (int it = 0; it < 4; ++it) {
        const int i  = tid + it * 256;       // float4 index 0..1023
        const float4 v = xsrc[i];
        const int px = i >> 4;               // (i*4)/64
        const int c0 = (i << 2) & 63;
        float* d = &xt[px * XPAD + c0];
        d[0] = v.x; d[1] = v.y; d[2] = v.z; d[3] = v.w;
    }
    __syncthreads();

    // attn chunk base for this wave: 16 consecutive t's, uniform address.
    const float* __restrict__ at = attnT + (size_t)b * (CC * CC) + th * 16;
    const float* __restrict__ xr = &xt[lane * XPAD];

    float4 a0 = make_float4(0.f, 0.f, 0.f, 0.f);
    float4 a1 = a0, a2 = a0, a3 = a0;

#pragma unroll 4
    for (int c = 0; c < CC; ++c) {
        const float xc = xr[c];
        const float4 w0 = *(const float4*)(at + c * CC + 0);
        const float4 w1 = *(const float4*)(at + c * CC + 4);
        const float4 w2 = *(const float4*)(at + c * CC + 8);
        const float4 w3 = *(const float4*)(at + c * CC + 12);
        a0.x = fmaf(xc, w0.x, a0.x); a0.y = fmaf(xc, w0.y, a0.y);
        a0.z = fmaf(xc, w0.z, a0.z); a0.w = fmaf(xc, w0.w, a0.w);
        a1.x = fmaf(xc, w1.x, a1.x); a1.y = fmaf(xc, w1.y, a1.y);
        a1.z = fmaf(xc, w1.z, a1.z); a1.w = fmaf(xc, w1.w, a1.w);
        a2.x = fmaf(xc, w2.x, a2.x); a2.y = fmaf(xc, w2.y, a2.y);
        a2.z = fmaf(xc, w2.z, a2.z); a2.w = fmaf(xc, w2.w, a2.w);
        a3.x = fmaf(xc, w3.x, a3.x); a3.y = fmaf(xc, w3.y, a3.y);
        a3.z = fmaf(xc, w3.z, a3.z); a3.w = fmaf(xc, w3.w, a3.w);
    }

    // Epilogue: exact GELU + 64 B contiguous store per thread.
    float* op = out + (pixbase + lane) * CC + th * 16;
    float4 g;
    g.x = gelu_exact(a0.x); g.y = gelu_exact(a0.y); g.z = gelu_exact(a0.z); g.w = gelu_exact(a0.w);
    ((float4*)op)[0] = g;
    g.x = gelu_exact(a1.x); g.y = gelu_exact(a1.y); g.z = gelu_exact(a1.z); g.w = gelu_exact(a1.w);
    ((float4*)op)[1] = g;
    g.x = gelu_exact(a2.x); g.y = gelu_exact(a2.y); g.z = gelu_exact(a2.z); g.w = gelu_exact(a2.w);
    ((float4*)op)[2] = g;
    g.x = gelu_exact(a3.x); g.y = gelu_exact(a3.y); g.z = gelu_exact(a3.z); g.w = gelu_exact(a3.w);
    ((float4*)op)[3] = g;
}

// ---------------------------------------------------------------------------
extern "C" void kernel_launch(void* const* d_in, const int* in_sizes, int n_in,
                              void* d_out, int out_size, void* d_ws, size_t ws_size,
                              hipStream_t stream) {
    const float* x     = (const float*)d_in[0];   // (16,256,256,64) fp32
    const float* w_qkv = (const float*)d_in[1];   // (32,16) fp32
    float* out   = (float*)d_out;                 // (16,256,256,64) fp32
    float* part  = (float*)d_ws;                  // 1 MiB
    float* attnT = part + PART_FLOATS;            // 256 KiB

    pool_partial<<<BB * NTOK * 16, 256, 0, stream>>>(x, part);
    attn_kernel<<<BB, 256, 0, stream>>>(part, w_qkv, attnT);
    out_kernel<<<BB * 256 * 4, 256, 0, stream>>>(x, attnT, out);
}